// Round 17
// baseline (43.926 us; speedup 1.0000x reference)
//
#include <hip/hip_runtime.h>
#include <hip/hip_bf16.h>

// InferenceLinear: out[m][n] = sum_k x[m][k] * (q[n][k]*qrange[n][k/256] + qmin[n][k/256])
// M=512, N=2048, K=4096, 16 groups of 256.
// R17: weight-resident restructure. Six schedule variants all ~35-37us -> the
// residual is traffic PLACEMENT: qweight (33.5MB int32, the big operand) was
// re-read 4x via L2/L3. Now each block owns an exclusive (n=64, k=512) W-slice:
// loads it ONCE from HBM, dequants into 64KB W-LDS, then loops m-tiles reading
// only x (small; per-XCD k-slice 1MB = L2-resident). No pack pass. Grid
// 32n x 8kc x 2mh = 512 blocks (kc=b&7=XCD), 512 thr, LDS 80KB -> 2 blocks/CU.
// Partials fp32 -> ws, deterministic reduce.

#define M_T 512
#define N_T 2048
#define K_T 4096
#define NGRP 16
#define KSPLIT 8
#define KC 512                       // k per block (= 2 quant groups)
#define BN 64
#define BM 128                       // m-tile
#define OUT_ELEMS (M_T * N_T)

typedef __attribute__((ext_vector_type(8))) short mfrag_t;           // 8 bf16
typedef __attribute__((ext_vector_type(8))) unsigned short u16x8;
typedef __attribute__((ext_vector_type(4))) float f32x4;

__device__ __forceinline__ unsigned short f2bf(float f) {
  union { __hip_bfloat16 h; unsigned short u; } c;
  c.h = __float2bfloat16(f);
  return c.u;
}

__global__ __launch_bounds__(512, 2) void wres_gemm_kernel(
    const float* __restrict__ x, const int* __restrict__ qw,
    const float* __restrict__ qrange, const float* __restrict__ qmin,
    float* __restrict__ dst) {
  // W: [64 rows][512 k] bf16, 16B slots swizzled phys = slot ^ (row&7)  (64KB)
  // X: [128 rows][64 k] bf16, same swizzle (8 slots/row)                (16KB)
  __shared__ __align__(16) unsigned short WL[BN * KC];
  __shared__ __align__(16) unsigned short XL[BM * 64];

  const int b = blockIdx.x;
  const int kc = b & 7;              // XCD id == k-chunk (b%8 round-robin)
  const int slot = b >> 3;           // 0..63
  const int xt = slot & 31;          // n-tile
  const int mh = slot >> 5;          // m-half (0..1)
  const int n0 = xt * BN;
  const int kbase = kc * KC;
  const int tid = threadIdx.x;
  const int lane = tid & 63;
  const int wv = tid >> 6;           // 0..7

  // ---- Phase A: load + dequant W tile (64 x 512 int32 -> bf16 LDS), once ----
  {
    const int wrow = tid >> 3;       // 0..63
    const int wc8 = tid & 7;         // 0..7
    const int* qrow = qw + (size_t)(n0 + wrow) * K_T + kbase;
    const float* qrp = qrange + (size_t)(n0 + wrow) * NGRP + kc * 2;
    const float* qmp = qmin + (size_t)(n0 + wrow) * NGRP + kc * 2;
    const float sc0 = qrp[0], mn0 = qmp[0];
    const float sc1 = qrp[1], mn1 = qmp[1];
    const int rx = wrow & 7;
#pragma unroll
    for (int c = 0; c < 4; ++c) {
      const int col = wc8 * 16 + c * 128;        // elem col, group g = c>>1
      const int4* q4 = (const int4*)(qrow + col);
      const int4 q0 = q4[0], q1 = q4[1], q2 = q4[2], q3 = q4[3];
      const float sc = (c < 2) ? sc0 : sc1;
      const float mn = (c < 2) ? mn0 : mn1;
      u16x8 p0, p1;
      p0[0] = f2bf((float)q0.x * sc + mn); p0[1] = f2bf((float)q0.y * sc + mn);
      p0[2] = f2bf((float)q0.z * sc + mn); p0[3] = f2bf((float)q0.w * sc + mn);
      p0[4] = f2bf((float)q1.x * sc + mn); p0[5] = f2bf((float)q1.y * sc + mn);
      p0[6] = f2bf((float)q1.z * sc + mn); p0[7] = f2bf((float)q1.w * sc + mn);
      p1[0] = f2bf((float)q2.x * sc + mn); p1[1] = f2bf((float)q2.y * sc + mn);
      p1[2] = f2bf((float)q2.z * sc + mn); p1[3] = f2bf((float)q2.w * sc + mn);
      p1[4] = f2bf((float)q3.x * sc + mn); p1[5] = f2bf((float)q3.y * sc + mn);
      p1[6] = f2bf((float)q3.z * sc + mn); p1[7] = f2bf((float)q3.w * sc + mn);
      const int s0 = (col >> 3) ^ rx;            // 16B-slot index in [0,64)
      const int s1 = ((col >> 3) + 1) ^ rx;
      *(u16x8*)&WL[wrow * KC + s0 * 8] = p0;
      *(u16x8*)&WL[wrow * KC + s1 * 8] = p1;
    }
  }

  // ---- compute mapping: 8 waves 4(M) x 2(N); wave tile 32x32 (2x2 frags) ----
  const int wm = (wv >> 1) * 32;     // 0,32,64,96
  const int wn = (wv & 1) * 32;      // 0,32
  const int lr = lane & 15;
  const int lq = lane >> 4;
  const int rxl = lr & 15 & 7;       // row&7 == lr&7 (wm,wn,f*16 mult of 16)

  // ---- X staging mapping: thread -> (row 0..127, seg 0..3 of 16 elems) ----
  const int xrow = tid >> 2;
  const int xseg = tid & 3;
  const int xrx = xrow & 7;
  const int xs0 = (xseg * 2) ^ xrx;
  const int xs1 = (xseg * 2 + 1) ^ xrx;

  float* pbase = dst + (size_t)kc * OUT_ELEMS;

#pragma unroll
  for (int mt = 0; mt < 2; ++mt) {
    const int m0g = mh * 256 + mt * 128;
    const float* xp = x + (size_t)(m0g + xrow) * K_T + kbase + xseg * 16;
    f32x4 acc[2][2] = {};

    for (int ks = 0; ks < 8; ++ks) {
      if (mt > 0 || ks > 0) __syncthreads();   // X readers done (also orders W writes once)

      // stage X[mt][ks]: 16 fp32 -> bf16 -> swizzled LDS
      {
        const float4* a4 = (const float4*)(xp + ks * 64);
        const float4 a0 = a4[0], a1 = a4[1], a2 = a4[2], a3 = a4[3];
        u16x8 p0, p1;
        p0[0] = f2bf(a0.x); p0[1] = f2bf(a0.y); p0[2] = f2bf(a0.z); p0[3] = f2bf(a0.w);
        p0[4] = f2bf(a1.x); p0[5] = f2bf(a1.y); p0[6] = f2bf(a1.z); p0[7] = f2bf(a1.w);
        p1[0] = f2bf(a2.x); p1[1] = f2bf(a2.y); p1[2] = f2bf(a2.z); p1[3] = f2bf(a2.w);
        p1[4] = f2bf(a3.x); p1[5] = f2bf(a3.y); p1[6] = f2bf(a3.z); p1[7] = f2bf(a3.w);
        *(u16x8*)&XL[xrow * 64 + xs0 * 8] = p0;
        *(u16x8*)&XL[xrow * 64 + xs1 * 8] = p1;
      }
      __syncthreads();

      // compute: 2 K-substeps of 32
#pragma unroll
      for (int kk = 0; kk < 2; ++kk) {
        const int sx = (kk * 4 + lq) ^ rxl;              // X slot [0,8)
        const int sw = (ks * 8 + kk * 4 + lq) ^ rxl;     // W slot [0,64)
        mfrag_t af[2], bf[2];
        af[0] = *(const mfrag_t*)&XL[(wm + lr) * 64 + sx * 8];
        af[1] = *(const mfrag_t*)&XL[(wm + 16 + lr) * 64 + sx * 8];
        bf[0] = *(const mfrag_t*)&WL[(wn + lr) * KC + sw * 8];
        bf[1] = *(const mfrag_t*)&WL[(wn + 16 + lr) * KC + sw * 8];
        acc[0][0] = __builtin_amdgcn_mfma_f32_16x16x32_bf16(af[0], bf[0], acc[0][0], 0, 0, 0);
        acc[0][1] = __builtin_amdgcn_mfma_f32_16x16x32_bf16(af[0], bf[1], acc[0][1], 0, 0, 0);
        acc[1][0] = __builtin_amdgcn_mfma_f32_16x16x32_bf16(af[1], bf[0], acc[1][0], 0, 0, 0);
        acc[1][1] = __builtin_amdgcn_mfma_f32_16x16x32_bf16(af[1], bf[1], acc[1][1], 0, 0, 0);
      }
    }

    // ---- store this m-tile's partial (plain coalesced stores) ----
    // C/D layout col=lane&15, row=(lane>>4)*4+reg (measured m89/m91)
#pragma unroll
    for (int fm = 0; fm < 2; ++fm) {
#pragma unroll
      for (int fn = 0; fn < 2; ++fn) {
        const int r0 = m0g + wm + fm * 16 + lq * 4;
        const int c = n0 + wn + fn * 16 + lr;
        float* op = pbase + (size_t)r0 * N_T + c;
        op[0 * (size_t)N_T] = acc[fm][fn][0];
        op[1 * (size_t)N_T] = acc[fm][fn][1];
        op[2 * (size_t)N_T] = acc[fm][fn][2];
        op[3 * (size_t)N_T] = acc[fm][fn][3];
      }
    }
  }
}

// ---- out[i] = sum_s partials[s][i], deterministic order ----
__global__ __launch_bounds__(256) void reduce_kernel(const float* __restrict__ ws,
                                                     float* __restrict__ out) {
  const int i4 = blockIdx.x * 256 + threadIdx.x;
  const size_t base = (size_t)i4 * 4;
  float4 a = *(const float4*)(ws + base);
#pragma unroll
  for (int s = 1; s < KSPLIT; ++s) {
    float4 b = *(const float4*)(ws + (size_t)s * OUT_ELEMS + base);
    a.x += b.x; a.y += b.y; a.z += b.z; a.w += b.w;
  }
  *(float4*)(out + base) = a;
}

// ---- fallback only (never expected to run): naive dot per output elem ----
__global__ void naive_kernel(const float* __restrict__ x, const int* __restrict__ qw,
                             const float* __restrict__ qrange, const float* __restrict__ qmin,
                             float* __restrict__ out) {
  const int idx = blockIdx.x * 256 + threadIdx.x;
  if (idx >= OUT_ELEMS) return;
  const int m = idx / N_T, n = idx % N_T;
  float s = 0.f;
  for (int g = 0; g < NGRP; ++g) {
    const float sc = qrange[n * NGRP + g], mn = qmin[n * NGRP + g];
    float d = 0.f, xs = 0.f;
    for (int k = g * 256; k < (g + 1) * 256; ++k) {
      d += x[(size_t)m * K_T + k] * (float)qw[(size_t)n * K_T + k];
      xs += x[(size_t)m * K_T + k];
    }
    s += d * sc + xs * mn;
  }
  out[idx] = s;
}

extern "C" void kernel_launch(void* const* d_in, const int* in_sizes, int n_in,
                              void* d_out, int out_size, void* d_ws, size_t ws_size,
                              hipStream_t stream) {
  const float* x = (const float*)d_in[0];
  const int* qw = (const int*)d_in[1];
  const float* qr = (const float*)d_in[2];
  const float* qm = (const float*)d_in[3];
  float* out = (float*)d_out;
  float* partials = (float*)d_ws;

  const size_t need = (size_t)KSPLIT * OUT_ELEMS * sizeof(float);
  if (ws_size >= need) {
    // grid: 32 n-tiles x 8 kc x 2 mh = 512 blocks
    wres_gemm_kernel<<<512, dim3(512, 1, 1), 0, stream>>>(x, qw, qr, qm, partials);
    reduce_kernel<<<OUT_ELEMS / 4 / 256, 256, 0, stream>>>(partials, out);
  } else {
    naive_kernel<<<(OUT_ELEMS + 255) / 256, 256, 0, stream>>>(x, qw, qr, qm, out);
  }
}

// Round 20
// 42.207 us; speedup vs baseline: 1.0407x; 1.0407x over previous
//
#include <hip/hip_runtime.h>
#include <hip/hip_bf16.h>

// InferenceLinear: out[m][n] = sum_k x[m][k] * (q[n][k]*qrange[n][k/256] + qmin[n][k/256])
// M=512, N=2048, K=4096, 16 groups of 256.
// R19 resubmit (infra failure, no signal). Cache-policy lever on the R14
// champion: nontemporal loads/stores for single-use streams (pack reads qw/x,
// GEMM partial stores, reduce partial loads); packed wsW/wsX + GEMM operand
// reads stay cached so each XCD's L2 keeps the 2.6MB operand slice. Structure:
// pack -> bf16 GEMM (gload_lds, 128x128, BK=64, KSPLIT=8, XCD decode) -> reduce.

#define M_T 512
#define N_T 2048
#define K_T 4096
#define NGRP 16
#define BM 128
#define BN 128
#define BK 64
#define OUT_ELEMS (M_T * N_T)
#define W_ELEMS (N_T * K_T)          // 8388608 bf16
#define X_ELEMS (M_T * K_T)          // 2097152 bf16

typedef __attribute__((ext_vector_type(8))) short mfrag_t;           // 8 bf16 (4 VGPR)
typedef __attribute__((ext_vector_type(8))) unsigned short u16x8;
typedef __attribute__((ext_vector_type(4))) float f32x4;
typedef __attribute__((ext_vector_type(4))) int i32x4;

__device__ __forceinline__ unsigned short f2bf(float f) {
  union { __hip_bfloat16 h; unsigned short u; } c;
  c.h = __float2bfloat16(f);
  return c.u;
}

// ---- pass 1: dequant W (int32 q -> bf16) + cast X (fp32 -> bf16) ----
// Single-use global reads are nontemporal (don't pollute L2); outputs cached.
__global__ __launch_bounds__(256) void pack_kernel(
    const float* __restrict__ x, const int* __restrict__ qw,
    const float* __restrict__ qrange, const float* __restrict__ qmin,
    unsigned short* __restrict__ wsW, unsigned short* __restrict__ wsX) {
  const int bid = blockIdx.x;
  const int tid = threadIdx.x;
  if (bid < (W_ELEMS / 8) / 256) {
    const int gidx = bid * 256 + tid;        // [0, 1048576)
    const int o = gidx >> 9;                 // 512 groups-of-8 per row
    const int k8 = gidx & 511;
    const int g = k8 >> 5;                   // 32 groups-of-8 per quant group
    const float sc = qrange[o * NGRP + g];
    const float mn = qmin[o * NGRP + g];
    const i32x4* q = (const i32x4*)(qw + ((size_t)o << 12) + (k8 << 3));
    const i32x4 q0 = __builtin_nontemporal_load(q);
    const i32x4 q1 = __builtin_nontemporal_load(q + 1);
    u16x8 p;
    p[0] = f2bf((float)q0[0] * sc + mn); p[1] = f2bf((float)q0[1] * sc + mn);
    p[2] = f2bf((float)q0[2] * sc + mn); p[3] = f2bf((float)q0[3] * sc + mn);
    p[4] = f2bf((float)q1[0] * sc + mn); p[5] = f2bf((float)q1[1] * sc + mn);
    p[6] = f2bf((float)q1[2] * sc + mn); p[7] = f2bf((float)q1[3] * sc + mn);
    *(u16x8*)(wsW + ((size_t)gidx << 3)) = p;
  } else {
    const int gidx = (bid - (W_ELEMS / 8) / 256) * 256 + tid;  // [0, 262144)
    const f32x4* a = (const f32x4*)(x + ((size_t)gidx << 3));
    const f32x4 a0 = __builtin_nontemporal_load(a);
    const f32x4 a1 = __builtin_nontemporal_load(a + 1);
    u16x8 p;
    p[0] = f2bf(a0[0]); p[1] = f2bf(a0[1]); p[2] = f2bf(a0[2]); p[3] = f2bf(a0[3]);
    p[4] = f2bf(a1[0]); p[5] = f2bf(a1[1]); p[6] = f2bf(a1[2]); p[7] = f2bf(a1[3]);
    *(u16x8*)(wsX + ((size_t)gidx << 3)) = p;
  }
}

// ---- pass 2: bf16 GEMM with global_load_lds staging; NT partial stores ----
template <int KSPLIT, bool XCDSWZ>
__global__ __launch_bounds__(512, 4) void dq_gemm_kernel(
    const unsigned short* __restrict__ wsX, const unsigned short* __restrict__ wsW,
    float* __restrict__ dst) {
  constexpr int KC = K_T / KSPLIT;
  constexpr int NTC = KC / BK;

  // physical layout: [row][slot^(row&7)], slot = 8-elem (16B) unit; linear fill
  __shared__ __align__(16) unsigned short As[BM * BK];
  __shared__ __align__(16) unsigned short Bs[BN * BK];

  const int tid = threadIdx.x;
  int xt, yt, kc;
  if (XCDSWZ) {
    const int b = blockIdx.x;
    kc = b & 7;                 // XCD id == k-chunk (assumes b%8 round-robin)
    const int slot = b >> 3;
    xt = slot & 15;             // n-tile
    yt = slot >> 4;             // m-tile
  } else {
    const int b = blockIdx.x;
    xt = b & 15;
    yt = (b >> 4) & 3;
    kc = b >> 6;
  }
  const int n0 = xt * BN;
  const int m0 = yt * BM;
  const int kbase = kc * KC;

  // compute mapping: 8 waves, 2(M) x 4(N); wave tile 64x32
  const int lane = tid & 63;
  const int wv = tid >> 6;
  const int wm = (wv >> 2) * 64;   // 0,64
  const int wn = (wv & 3) * 32;    // 0,32,64,96
  const int lr = lane & 15;
  const int lq = lane >> 4;
  const int rxl = lr & 7;  // read-side xor (row&7 == lr&7: wm,wn,f*16 mult of 8)

  // staging mapping for global_load_lds (16B/lane): wave wv covers rows
  // [wv*16, wv*16+16) in two 1KB chunks (8 rows each). lane l -> row += l>>3,
  // phys slot = l&7. LDS[row][p] holds logical data[p ^ (row&7)]; row&7 == l>>3,
  // so per-lane GLOBAL source col16 = (l&7) ^ (l>>3). Dest linear = base+lane*16.
  const int swzcol = (((lane & 7) ^ (lane >> 3)) << 3);       // elem offset
  const int r0 = wv * 16 + (lane >> 3);                        // chunk0 row
  const int r1 = r0 + 8;                                       // chunk1 row
  const unsigned short* gA0 = wsX + (size_t)(m0 + r0) * K_T + kbase + swzcol;
  const unsigned short* gA1 = wsX + (size_t)(m0 + r1) * K_T + kbase + swzcol;
  const unsigned short* gB0 = wsW + (size_t)(n0 + r0) * K_T + kbase + swzcol;
  const unsigned short* gB1 = wsW + (size_t)(n0 + r1) * K_T + kbase + swzcol;
  unsigned short* lA0 = &As[wv * 1024];        // elems; 2KB per wave
  unsigned short* lA1 = &As[wv * 1024 + 512];
  unsigned short* lB0 = &Bs[wv * 1024];
  unsigned short* lB1 = &Bs[wv * 1024 + 512];

#define STAGE(T)                                                              \
  do {                                                                        \
    const size_t o_ = (size_t)(T) * BK;                                       \
    __builtin_amdgcn_global_load_lds(                                         \
        (const __attribute__((address_space(1))) void*)(gA0 + o_),            \
        (__attribute__((address_space(3))) void*)lA0, 16, 0, 0);              \
    __builtin_amdgcn_global_load_lds(                                         \
        (const __attribute__((address_space(1))) void*)(gA1 + o_),            \
        (__attribute__((address_space(3))) void*)lA1, 16, 0, 0);              \
    __builtin_amdgcn_global_load_lds(                                         \
        (const __attribute__((address_space(1))) void*)(gB0 + o_),            \
        (__attribute__((address_space(3))) void*)lB0, 16, 0, 0);              \
    __builtin_amdgcn_global_load_lds(                                         \
        (const __attribute__((address_space(1))) void*)(gB1 + o_),            \
        (__attribute__((address_space(3))) void*)lB1, 16, 0, 0);              \
  } while (0)

  f32x4 acc[4][2] = {};

  STAGE(0);
  for (int t = 0; t < NTC; ++t) {
    __syncthreads();  // drains vmcnt(0): staged tile visible to all waves

#pragma unroll
    for (int kk = 0; kk < 2; ++kk) {
      const int so = ((kk * 4 + lq) ^ rxl) << 3;
      mfrag_t af[4], bf[2];
#pragma unroll
      for (int fm = 0; fm < 4; ++fm)
        af[fm] = *(const mfrag_t*)&As[(wm + fm * 16 + lr) * BK + so];
#pragma unroll
      for (int fn = 0; fn < 2; ++fn)
        bf[fn] = *(const mfrag_t*)&Bs[(wn + fn * 16 + lr) * BK + so];
#pragma unroll
      for (int fm = 0; fm < 4; ++fm)
#pragma unroll
        for (int fn = 0; fn < 2; ++fn)
          acc[fm][fn] = __builtin_amdgcn_mfma_f32_16x16x32_bf16(af[fm], bf[fn], acc[fm][fn], 0, 0, 0);
    }

    if (t + 1 < NTC) {
      __syncthreads();  // all waves done reading before overwrite
      STAGE(t + 1);
    }
  }
#undef STAGE

  // ---- epilogue: NONTEMPORAL stores of partials (single-use stream) ----
  // C/D layout col=lane&15, row=(lane>>4)*4+reg (measured m89/m91)
  float* base = dst + (size_t)kc * OUT_ELEMS;
#pragma unroll
  for (int fm = 0; fm < 4; ++fm) {
#pragma unroll
    for (int fn = 0; fn < 2; ++fn) {
      const int rr = m0 + wm + fm * 16 + lq * 4;
      const int c = n0 + wn + fn * 16 + lr;
      float* op = base + (size_t)rr * N_T + c;
      __builtin_nontemporal_store(acc[fm][fn][0], op + 0 * (size_t)N_T);
      __builtin_nontemporal_store(acc[fm][fn][1], op + 1 * (size_t)N_T);
      __builtin_nontemporal_store(acc[fm][fn][2], op + 2 * (size_t)N_T);
      __builtin_nontemporal_store(acc[fm][fn][3], op + 3 * (size_t)N_T);
    }
  }
}

// ---- pass 3: out[i] = sum_s partials[s][i] (NT loads), deterministic ----
template <int KSPLIT>
__global__ __launch_bounds__(256) void reduce_kernel(const float* __restrict__ ws,
                                                     float* __restrict__ out) {
  const int i4 = blockIdx.x * 256 + threadIdx.x;
  const size_t base = (size_t)i4 * 4;
  f32x4 a = __builtin_nontemporal_load((const f32x4*)(ws + base));
#pragma unroll
  for (int s = 1; s < KSPLIT; ++s) {
    f32x4 b = __builtin_nontemporal_load(
        (const f32x4*)(ws + (size_t)s * OUT_ELEMS + base));
    a += b;
  }
  *(f32x4*)(out + base) = a;
}

// ---- fallback only (never expected to run): naive dot per output elem ----
__global__ void naive_kernel(const float* __restrict__ x, const int* __restrict__ qw,
                             const float* __restrict__ qrange, const float* __restrict__ qmin,
                             float* __restrict__ out) {
  const int idx = blockIdx.x * 256 + threadIdx.x;
  if (idx >= OUT_ELEMS) return;
  const int m = idx / N_T, n = idx % N_T;
  float s = 0.f;
  for (int g = 0; g < NGRP; ++g) {
    const float sc = qrange[n * NGRP + g], mn = qmin[n * NGRP + g];
    float d = 0.f, xs = 0.f;
    for (int k = g * 256; k < (g + 1) * 256; ++k) {
      d += x[(size_t)m * K_T + k] * (float)qw[(size_t)n * K_T + k];
      xs += x[(size_t)m * K_T + k];
    }
    s += d * sc + xs * mn;
  }
  out[idx] = s;
}

extern "C" void kernel_launch(void* const* d_in, const int* in_sizes, int n_in,
                              void* d_out, int out_size, void* d_ws, size_t ws_size,
                              hipStream_t stream) {
  const float* x = (const float*)d_in[0];
  const int* qw = (const int*)d_in[1];
  const float* qr = (const float*)d_in[2];
  const float* qm = (const float*)d_in[3];
  float* out = (float*)d_out;

  constexpr int KS = 8;
  unsigned short* wsW = (unsigned short*)d_ws;
  unsigned short* wsX = wsW + W_ELEMS;
  float* partials = (float*)(wsX + X_ELEMS);
  const size_t need = (size_t)W_ELEMS * 2 + (size_t)X_ELEMS * 2 +
                      (size_t)KS * OUT_ELEMS * sizeof(float);
  if (ws_size >= need) {
    const int packblk = (W_ELEMS / 8) / 256 + (X_ELEMS / 8) / 256;  // 4096+1024
    pack_kernel<<<packblk, 256, 0, stream>>>(x, qw, qr, qm, wsW, wsX);
    const int nblk = (N_T / BN) * (M_T / BM) * KS;  // 512
    dq_gemm_kernel<KS, true><<<nblk, dim3(512, 1, 1), 0, stream>>>(wsX, wsW, partials);
    reduce_kernel<KS><<<OUT_ELEMS / 4 / 256, 256, 0, stream>>>(partials, out);
  } else {
    naive_kernel<<<(OUT_ELEMS + 255) / 256, 256, 0, stream>>>(x, qw, qr, qm, out);
  }
}